// Round 1
// baseline (1900.747 us; speedup 1.0000x reference)
//
#include <hip/hip_runtime.h>
#include <math.h>

// GCN: h = D^-1/2 (A+I) D^-1/2 (x W) + b, 3 layers + classifier.
// N = 100000 nodes, E = 3.2M edges, feats 128 -> 4 -> 4 -> 2 -> 4.
// Self-loop contribution handled analytically in node epilogues (no atomics).

__global__ void init_kernel(float* __restrict__ deg, float4* __restrict__ B,
                            float2* __restrict__ D, int n) {
    int v = blockIdx.x * blockDim.x + threadIdx.x;
    if (v >= n) return;
    deg[v] = 1.0f;                       // self-loop contribution to degree
    B[v] = make_float4(0.f, 0.f, 0.f, 0.f);
    D[v] = make_float2(0.f, 0.f);
}

__global__ void deg_kernel(const int* __restrict__ col, float* __restrict__ deg, int E) {
    int e = blockIdx.x * blockDim.x + threadIdx.x;
    if (e >= E) return;
    atomicAdd(&deg[col[e]], 1.0f);
}

__global__ void dinv_kernel(float* __restrict__ deg, int n) {
    int v = blockIdx.x * blockDim.x + threadIdx.x;
    if (v >= n) return;
    deg[v] = rsqrtf(deg[v]);             // deg >= 1 always (self-loops)
}

// x [n,128] @ W1 [128,4] -> A [n,4]. One wave (64 lanes) per node; coalesced
// 512B row read; shfl_xor tree reduction for the 4 outputs.
__global__ void mm1_kernel(const float* __restrict__ x, const float* __restrict__ W1,
                           float4* __restrict__ A, int n) {
    int gid  = blockIdx.x * blockDim.x + threadIdx.x;
    int lane = threadIdx.x & 63;
    int v    = gid >> 6;
    if (v >= n) return;                  // whole wave exits together
    const float x0 = x[(size_t)v * 128 + lane];
    const float x1 = x[(size_t)v * 128 + 64 + lane];
    float p0 = x0 * W1[lane * 4 + 0] + x1 * W1[(lane + 64) * 4 + 0];
    float p1 = x0 * W1[lane * 4 + 1] + x1 * W1[(lane + 64) * 4 + 1];
    float p2 = x0 * W1[lane * 4 + 2] + x1 * W1[(lane + 64) * 4 + 2];
    float p3 = x0 * W1[lane * 4 + 3] + x1 * W1[(lane + 64) * 4 + 3];
#pragma unroll
    for (int off = 32; off > 0; off >>= 1) {
        p0 += __shfl_xor(p0, off);
        p1 += __shfl_xor(p1, off);
        p2 += __shfl_xor(p2, off);
        p3 += __shfl_xor(p3, off);
    }
    if (lane == 0) A[v] = make_float4(p0, p1, p2, p3);
}

// agg[row] += T[col] * dinv[row]*dinv[col], 4 features per edge.
__global__ void edge4_kernel(const int* __restrict__ row, const int* __restrict__ col,
                             const float* __restrict__ dinv, const float4* __restrict__ T,
                             float* __restrict__ AGG, int E) {
    int e = blockIdx.x * blockDim.x + threadIdx.x;
    if (e >= E) return;
    int r = row[e], c = col[e];
    float nrm = dinv[r] * dinv[c];
    float4 t = T[c];
    atomicAdd(&AGG[r * 4 + 0], t.x * nrm);
    atomicAdd(&AGG[r * 4 + 1], t.y * nrm);
    atomicAdd(&AGG[r * 4 + 2], t.z * nrm);
    atomicAdd(&AGG[r * 4 + 3], t.w * nrm);
}

// 2-feature variant for layer 3.
__global__ void edge2_kernel(const int* __restrict__ row, const int* __restrict__ col,
                             const float* __restrict__ dinv, const float2* __restrict__ T,
                             float* __restrict__ AGG, int E) {
    int e = blockIdx.x * blockDim.x + threadIdx.x;
    if (e >= E) return;
    int r = row[e], c = col[e];
    float nrm = dinv[r] * dinv[c];
    float2 t = T[c];
    atomicAdd(&AGG[r * 2 + 0], t.x * nrm);
    atomicAdd(&AGG[r * 2 + 1], t.y * nrm);
}

// h1 = tanh(agg1 + selfloop + b1); A <- h1 @ W2 (4x4); B <- 0 for next layer.
__global__ void node1_kernel(const float* __restrict__ dinv, float4* __restrict__ A,
                             float4* __restrict__ B, const float* __restrict__ b1,
                             const float* __restrict__ W2, int n) {
    int v = blockIdx.x * blockDim.x + threadIdx.x;
    if (v >= n) return;
    float d = dinv[v], d2 = d * d;
    float4 t = A[v];
    float4 a = B[v];
    float h0 = tanhf(a.x + t.x * d2 + b1[0]);
    float h1 = tanhf(a.y + t.y * d2 + b1[1]);
    float h2 = tanhf(a.z + t.z * d2 + b1[2]);
    float h3 = tanhf(a.w + t.w * d2 + b1[3]);
    float4 t2;
    t2.x = h0 * W2[0] + h1 * W2[4] + h2 * W2[8]  + h3 * W2[12];
    t2.y = h0 * W2[1] + h1 * W2[5] + h2 * W2[9]  + h3 * W2[13];
    t2.z = h0 * W2[2] + h1 * W2[6] + h2 * W2[10] + h3 * W2[14];
    t2.w = h0 * W2[3] + h1 * W2[7] + h2 * W2[11] + h3 * W2[15];
    A[v] = t2;
    B[v] = make_float4(0.f, 0.f, 0.f, 0.f);
}

// h2 = tanh(agg2 + selfloop + b2); C <- h2 @ W3 (4x2).
__global__ void node2_kernel(const float* __restrict__ dinv, const float4* __restrict__ A,
                             const float4* __restrict__ B, const float* __restrict__ b2,
                             const float* __restrict__ W3, float2* __restrict__ C, int n) {
    int v = blockIdx.x * blockDim.x + threadIdx.x;
    if (v >= n) return;
    float d = dinv[v], d2 = d * d;
    float4 t = A[v];
    float4 a = B[v];
    float h0 = tanhf(a.x + t.x * d2 + b2[0]);
    float h1 = tanhf(a.y + t.y * d2 + b2[1]);
    float h2 = tanhf(a.z + t.z * d2 + b2[2]);
    float h3 = tanhf(a.w + t.w * d2 + b2[3]);
    float2 t3;
    t3.x = h0 * W3[0] + h1 * W3[2] + h2 * W3[4] + h3 * W3[6];
    t3.y = h0 * W3[1] + h1 * W3[3] + h2 * W3[5] + h3 * W3[7];
    C[v] = t3;
}

// h3 = tanh(agg3 + selfloop + b3); out = h3 @ Wc + bc. Writes both outputs.
__global__ void node3_kernel(const float* __restrict__ dinv, const float2* __restrict__ C,
                             const float2* __restrict__ D, const float* __restrict__ b3,
                             const float* __restrict__ Wc, const float* __restrict__ bc,
                             float* __restrict__ out, int n) {
    int v = blockIdx.x * blockDim.x + threadIdx.x;
    if (v >= n) return;
    float d = dinv[v], d2 = d * d;
    float2 t = C[v];
    float2 a = D[v];
    float h0 = tanhf(a.x + t.x * d2 + b3[0]);
    float h1 = tanhf(a.y + t.y * d2 + b3[1]);
    float4 o;
    o.x = h0 * Wc[0] + h1 * Wc[4] + bc[0];
    o.y = h0 * Wc[1] + h1 * Wc[5] + bc[1];
    o.z = h0 * Wc[2] + h1 * Wc[6] + bc[2];
    o.w = h0 * Wc[3] + h1 * Wc[7] + bc[3];
    ((float4*)out)[v] = o;                               // out: [n,4]
    ((float2*)(out + (size_t)n * 4))[v] = make_float2(h0, h1);  // h3: [n,2]
}

extern "C" void kernel_launch(void* const* d_in, const int* in_sizes, int n_in,
                              void* d_out, int out_size, void* d_ws, size_t ws_size,
                              hipStream_t stream) {
    const float* x  = (const float*)d_in[0];
    const int*   ei = (const int*)  d_in[1];
    const float* W1 = (const float*)d_in[2];
    const float* b1 = (const float*)d_in[3];
    const float* W2 = (const float*)d_in[4];
    const float* b2 = (const float*)d_in[5];
    const float* W3 = (const float*)d_in[6];
    const float* b3 = (const float*)d_in[7];
    const float* Wc = (const float*)d_in[8];
    const float* bc = (const float*)d_in[9];

    const int n = in_sizes[0] / 128;
    const int E = in_sizes[1] / 2;
    const int* row = ei;       // edge_index[0] = destination (segment ids)
    const int* col = ei + E;   // edge_index[1] = source (gather)

    float* ws = (float*)d_ws;
    float4* A    = (float4*)ws;                        // [n,4] pre-agg features
    float4* B    = (float4*)(ws + (size_t)n * 4);      // [n,4] aggregator
    float2* C    = (float2*)(ws + (size_t)n * 8);      // [n,2] pre-agg features L3
    float2* D    = (float2*)(ws + (size_t)n * 10);     // [n,2] aggregator L3
    float*  dinv = ws + (size_t)n * 12;                // deg -> dinv in place
    float*  outp = (float*)d_out;

    const int nb_n = (n + 255) / 256;
    const int nb_e = (E + 255) / 256;
    const int nb_mm = ((size_t)n * 64 + 255) / 256;

    init_kernel<<<nb_n, 256, 0, stream>>>(dinv, B, D, n);
    deg_kernel<<<nb_e, 256, 0, stream>>>(col, dinv, E);
    dinv_kernel<<<nb_n, 256, 0, stream>>>(dinv, n);
    mm1_kernel<<<nb_mm, 256, 0, stream>>>(x, W1, A, n);

    edge4_kernel<<<nb_e, 256, 0, stream>>>(row, col, dinv, A, (float*)B, E);
    node1_kernel<<<nb_n, 256, 0, stream>>>(dinv, A, B, b1, W2, n);

    edge4_kernel<<<nb_e, 256, 0, stream>>>(row, col, dinv, A, (float*)B, E);
    node2_kernel<<<nb_n, 256, 0, stream>>>(dinv, A, B, b2, W3, C, n);

    edge2_kernel<<<nb_e, 256, 0, stream>>>(row, col, dinv, C, (float*)D, E);
    node3_kernel<<<nb_n, 256, 0, stream>>>(dinv, C, D, b3, Wc, bc, outp, n);
}

// Round 2
// 521.259 us; speedup vs baseline: 3.6465x; 3.6465x over previous
//
#include <hip/hip_runtime.h>
#include <math.h>

// GCN: h = D^-1/2 (A+I) D^-1/2 (x W) + b, 3 layers + classifier.
// N = 100000 nodes, E = 3.2M edges, feats 128 -> 4 -> 4 -> 2 -> 4.
//
// Round 2: device-scope fp32 atomics cost ~32B memory-side writes each
// (~20 G atomics/s measured). Round 1 did 11 atomics/edge. Now: build a
// transposed-ELL adjacency (2 int atomics/edge), then pull-based gather
// aggregation with ZERO value atomics. Features pre-scaled by dinv[src]
// so edge loops are pure sums; node epilogues fused into agg kernels.

#define ELL_C   64
#define OVF_CAP 32768

// ---------------- fast path ----------------

__global__ __launch_bounds__(256) void init2_kernel(int* __restrict__ deg, int* __restrict__ cnt,
                                                    float4* __restrict__ B, float2* __restrict__ D,
                                                    int* __restrict__ ovfc, int n) {
    int v = blockIdx.x * blockDim.x + threadIdx.x;
    if (v == 0) *ovfc = 0;
    if (v >= n) return;
    deg[v] = 0;
    cnt[v] = 0;
    B[v] = make_float4(0.f, 0.f, 0.f, 0.f);
    D[v] = make_float2(0.f, 0.f);
}

// One pass over edges: deg histogram (col) + ELL scatter (row) with overflow list.
__global__ __launch_bounds__(256) void build_kernel(const int* __restrict__ row, const int* __restrict__ col,
                                                    int* __restrict__ deg, int* __restrict__ cnt,
                                                    int* __restrict__ slots, int* __restrict__ ovfc,
                                                    int2* __restrict__ ovf, int n, int E) {
    int e = blockIdx.x * blockDim.x + threadIdx.x;
    if (e >= E) return;
    int r = row[e], c = col[e];
    atomicAdd(&deg[c], 1);
    int pos = atomicAdd(&cnt[r], 1);
    if (pos < ELL_C) {
        slots[(size_t)pos * n + r] = c;           // transposed ELL: coalesced reads later
    } else {
        int i = atomicAdd(ovfc, 1);
        if (i < OVF_CAP) ovf[i] = make_int2(r, c);
    }
}

__global__ __launch_bounds__(256) void dinv2_kernel(const int* __restrict__ deg, float* __restrict__ dinv, int n) {
    int v = blockIdx.x * blockDim.x + threadIdx.x;
    if (v >= n) return;
    dinv[v] = rsqrtf((float)(deg[v] + 1));        // +1 self-loop
}

// x [n,128] @ W1 [128,4] -> Td1 [n,4], pre-scaled by dinv[v].
// One wave per node; coalesced 512B row read; shfl_xor reduction.
__global__ __launch_bounds__(256) void mm1_kernel(const float* __restrict__ x, const float* __restrict__ W1,
                                                  const float* __restrict__ dinv, float4* __restrict__ Td1, int n) {
    int gid  = blockIdx.x * blockDim.x + threadIdx.x;
    int lane = threadIdx.x & 63;
    int v    = gid >> 6;
    if (v >= n) return;
    const float x0 = x[(size_t)v * 128 + lane];
    const float x1 = x[(size_t)v * 128 + 64 + lane];
    float p0 = x0 * W1[lane * 4 + 0] + x1 * W1[(lane + 64) * 4 + 0];
    float p1 = x0 * W1[lane * 4 + 1] + x1 * W1[(lane + 64) * 4 + 1];
    float p2 = x0 * W1[lane * 4 + 2] + x1 * W1[(lane + 64) * 4 + 2];
    float p3 = x0 * W1[lane * 4 + 3] + x1 * W1[(lane + 64) * 4 + 3];
#pragma unroll
    for (int off = 32; off > 0; off >>= 1) {
        p0 += __shfl_xor(p0, off);
        p1 += __shfl_xor(p1, off);
        p2 += __shfl_xor(p2, off);
        p3 += __shfl_xor(p3, off);
    }
    if (lane == 0) {
        float d = dinv[v];
        Td1[v] = make_float4(p0 * d, p1 * d, p2 * d, p3 * d);
    }
}

// Overflow edges (usually none): atomic add of Td[src] into partial buffer.
__global__ __launch_bounds__(256) void ovf4_kernel(const int* __restrict__ ovfc, const int2* __restrict__ ovf,
                                                   const float4* __restrict__ Td, float* __restrict__ B) {
    int e = blockIdx.x * blockDim.x + threadIdx.x;
    int m = *ovfc; if (m > OVF_CAP) m = OVF_CAP;
    if (e >= m) return;
    int2 rc = ovf[e];
    float4 t = Td[rc.y];
    atomicAdd(&B[rc.x * 4 + 0], t.x);
    atomicAdd(&B[rc.x * 4 + 1], t.y);
    atomicAdd(&B[rc.x * 4 + 2], t.z);
    atomicAdd(&B[rc.x * 4 + 3], t.w);
}

__global__ __launch_bounds__(256) void ovf2_kernel(const int* __restrict__ ovfc, const int2* __restrict__ ovf,
                                                   const float2* __restrict__ Td, float* __restrict__ D) {
    int e = blockIdx.x * blockDim.x + threadIdx.x;
    int m = *ovfc; if (m > OVF_CAP) m = OVF_CAP;
    if (e >= m) return;
    int2 rc = ovf[e];
    float2 t = Td[rc.y];
    atomicAdd(&D[rc.x * 2 + 0], t.x);
    atomicAdd(&D[rc.x * 2 + 1], t.y);
}

// Pull aggregation + layer-1 epilogue: h1 = tanh(dinv*(sum + self) + b1), Td2 = (h1@W2)*dinv.
__global__ __launch_bounds__(256) void agg_node1(const int* __restrict__ cnt, const int* __restrict__ slots,
                                                 const float* __restrict__ dinv, const float4* __restrict__ Td1,
                                                 float4* __restrict__ B, const float* __restrict__ b1,
                                                 const float* __restrict__ W2, float4* __restrict__ Td2, int n) {
    int v = blockIdx.x * blockDim.x + threadIdx.x;
    if (v >= n) return;
    int k = cnt[v]; if (k > ELL_C) k = ELL_C;
    float4 s = B[v];                               // overflow partial (normally 0)
    for (int j = 0; j < k; ++j) {
        int c = slots[(size_t)j * n + v];
        float4 t = Td1[c];
        s.x += t.x; s.y += t.y; s.z += t.z; s.w += t.w;
    }
    float4 t0 = Td1[v];                            // self-loop: t[v]*dinv[v]^2 = Td1[v]*dinv[v]
    s.x += t0.x; s.y += t0.y; s.z += t0.z; s.w += t0.w;
    float d = dinv[v];
    float h0 = tanhf(d * s.x + b1[0]);
    float h1 = tanhf(d * s.y + b1[1]);
    float h2 = tanhf(d * s.z + b1[2]);
    float h3 = tanhf(d * s.w + b1[3]);
    float4 o;
    o.x = (h0 * W2[0] + h1 * W2[4] + h2 * W2[8]  + h3 * W2[12]) * d;
    o.y = (h0 * W2[1] + h1 * W2[5] + h2 * W2[9]  + h3 * W2[13]) * d;
    o.z = (h0 * W2[2] + h1 * W2[6] + h2 * W2[10] + h3 * W2[14]) * d;
    o.w = (h0 * W2[3] + h1 * W2[7] + h2 * W2[11] + h3 * W2[15]) * d;
    Td2[v] = o;
    B[v] = make_float4(0.f, 0.f, 0.f, 0.f);        // reset for layer-2 overflow
}

// Layer-2: h2 = tanh(dinv*(sum + self) + b2), Td3 = (h2@W3)*dinv  (4 -> 2).
__global__ __launch_bounds__(256) void agg_node2(const int* __restrict__ cnt, const int* __restrict__ slots,
                                                 const float* __restrict__ dinv, const float4* __restrict__ Td2,
                                                 const float4* __restrict__ B, const float* __restrict__ b2,
                                                 const float* __restrict__ W3, float2* __restrict__ Td3, int n) {
    int v = blockIdx.x * blockDim.x + threadIdx.x;
    if (v >= n) return;
    int k = cnt[v]; if (k > ELL_C) k = ELL_C;
    float4 s = B[v];
    for (int j = 0; j < k; ++j) {
        int c = slots[(size_t)j * n + v];
        float4 t = Td2[c];
        s.x += t.x; s.y += t.y; s.z += t.z; s.w += t.w;
    }
    float4 t0 = Td2[v];
    s.x += t0.x; s.y += t0.y; s.z += t0.z; s.w += t0.w;
    float d = dinv[v];
    float h0 = tanhf(d * s.x + b2[0]);
    float h1 = tanhf(d * s.y + b2[1]);
    float h2 = tanhf(d * s.z + b2[2]);
    float h3 = tanhf(d * s.w + b2[3]);
    float2 o;
    o.x = (h0 * W3[0] + h1 * W3[2] + h2 * W3[4] + h3 * W3[6]) * d;
    o.y = (h0 * W3[1] + h1 * W3[3] + h2 * W3[5] + h3 * W3[7]) * d;
    Td3[v] = o;
}

// Layer-3 + classifier: h3 = tanh(dinv*(sum + self) + b3); out = h3@Wc + bc.
__global__ __launch_bounds__(256) void agg_node3(const int* __restrict__ cnt, const int* __restrict__ slots,
                                                 const float* __restrict__ dinv, const float2* __restrict__ Td3,
                                                 const float2* __restrict__ D, const float* __restrict__ b3,
                                                 const float* __restrict__ Wc, const float* __restrict__ bc,
                                                 float* __restrict__ out, int n) {
    int v = blockIdx.x * blockDim.x + threadIdx.x;
    if (v >= n) return;
    int k = cnt[v]; if (k > ELL_C) k = ELL_C;
    float2 s = D[v];
    for (int j = 0; j < k; ++j) {
        int c = slots[(size_t)j * n + v];
        float2 t = Td3[c];
        s.x += t.x; s.y += t.y;
    }
    float2 t0 = Td3[v];
    s.x += t0.x; s.y += t0.y;
    float d = dinv[v];
    float h0 = tanhf(d * s.x + b3[0]);
    float h1 = tanhf(d * s.y + b3[1]);
    float4 o;
    o.x = h0 * Wc[0] + h1 * Wc[4] + bc[0];
    o.y = h0 * Wc[1] + h1 * Wc[5] + bc[1];
    o.z = h0 * Wc[2] + h1 * Wc[6] + bc[2];
    o.w = h0 * Wc[3] + h1 * Wc[7] + bc[3];
    ((float4*)out)[v] = o;
    ((float2*)(out + (size_t)n * 4))[v] = make_float2(h0, h1);
}

// ---------------- fallback path (round-1, atomic-based) ----------------

__global__ void fb_init(float* __restrict__ deg, float4* __restrict__ B, float2* __restrict__ D, int n) {
    int v = blockIdx.x * blockDim.x + threadIdx.x;
    if (v >= n) return;
    deg[v] = 1.0f;
    B[v] = make_float4(0.f, 0.f, 0.f, 0.f);
    D[v] = make_float2(0.f, 0.f);
}
__global__ void fb_deg(const int* __restrict__ col, float* __restrict__ deg, int E) {
    int e = blockIdx.x * blockDim.x + threadIdx.x;
    if (e >= E) return;
    atomicAdd(&deg[col[e]], 1.0f);
}
__global__ void fb_dinv(float* __restrict__ deg, int n) {
    int v = blockIdx.x * blockDim.x + threadIdx.x;
    if (v >= n) return;
    deg[v] = rsqrtf(deg[v]);
}
__global__ void fb_mm1(const float* __restrict__ x, const float* __restrict__ W1, float4* __restrict__ A, int n) {
    int gid  = blockIdx.x * blockDim.x + threadIdx.x;
    int lane = threadIdx.x & 63;
    int v    = gid >> 6;
    if (v >= n) return;
    const float x0 = x[(size_t)v * 128 + lane];
    const float x1 = x[(size_t)v * 128 + 64 + lane];
    float p0 = x0 * W1[lane * 4 + 0] + x1 * W1[(lane + 64) * 4 + 0];
    float p1 = x0 * W1[lane * 4 + 1] + x1 * W1[(lane + 64) * 4 + 1];
    float p2 = x0 * W1[lane * 4 + 2] + x1 * W1[(lane + 64) * 4 + 2];
    float p3 = x0 * W1[lane * 4 + 3] + x1 * W1[(lane + 64) * 4 + 3];
#pragma unroll
    for (int off = 32; off > 0; off >>= 1) {
        p0 += __shfl_xor(p0, off); p1 += __shfl_xor(p1, off);
        p2 += __shfl_xor(p2, off); p3 += __shfl_xor(p3, off);
    }
    if (lane == 0) A[v] = make_float4(p0, p1, p2, p3);
}
__global__ void fb_edge4(const int* __restrict__ row, const int* __restrict__ col,
                         const float* __restrict__ dinv, const float4* __restrict__ T,
                         float* __restrict__ AGG, int E) {
    int e = blockIdx.x * blockDim.x + threadIdx.x;
    if (e >= E) return;
    int r = row[e], c = col[e];
    float nrm = dinv[r] * dinv[c];
    float4 t = T[c];
    atomicAdd(&AGG[r * 4 + 0], t.x * nrm);
    atomicAdd(&AGG[r * 4 + 1], t.y * nrm);
    atomicAdd(&AGG[r * 4 + 2], t.z * nrm);
    atomicAdd(&AGG[r * 4 + 3], t.w * nrm);
}
__global__ void fb_edge2(const int* __restrict__ row, const int* __restrict__ col,
                         const float* __restrict__ dinv, const float2* __restrict__ T,
                         float* __restrict__ AGG, int E) {
    int e = blockIdx.x * blockDim.x + threadIdx.x;
    if (e >= E) return;
    int r = row[e], c = col[e];
    float nrm = dinv[r] * dinv[c];
    float2 t = T[c];
    atomicAdd(&AGG[r * 2 + 0], t.x * nrm);
    atomicAdd(&AGG[r * 2 + 1], t.y * nrm);
}
__global__ void fb_node1(const float* __restrict__ dinv, float4* __restrict__ A, float4* __restrict__ B,
                         const float* __restrict__ b1, const float* __restrict__ W2, int n) {
    int v = blockIdx.x * blockDim.x + threadIdx.x;
    if (v >= n) return;
    float d = dinv[v], d2 = d * d;
    float4 t = A[v]; float4 a = B[v];
    float h0 = tanhf(a.x + t.x * d2 + b1[0]);
    float h1 = tanhf(a.y + t.y * d2 + b1[1]);
    float h2 = tanhf(a.z + t.z * d2 + b1[2]);
    float h3 = tanhf(a.w + t.w * d2 + b1[3]);
    float4 t2;
    t2.x = h0 * W2[0] + h1 * W2[4] + h2 * W2[8]  + h3 * W2[12];
    t2.y = h0 * W2[1] + h1 * W2[5] + h2 * W2[9]  + h3 * W2[13];
    t2.z = h0 * W2[2] + h1 * W2[6] + h2 * W2[10] + h3 * W2[14];
    t2.w = h0 * W2[3] + h1 * W2[7] + h2 * W2[11] + h3 * W2[15];
    A[v] = t2;
    B[v] = make_float4(0.f, 0.f, 0.f, 0.f);
}
__global__ void fb_node2(const float* __restrict__ dinv, const float4* __restrict__ A, const float4* __restrict__ B,
                         const float* __restrict__ b2, const float* __restrict__ W3, float2* __restrict__ C, int n) {
    int v = blockIdx.x * blockDim.x + threadIdx.x;
    if (v >= n) return;
    float d = dinv[v], d2 = d * d;
    float4 t = A[v]; float4 a = B[v];
    float h0 = tanhf(a.x + t.x * d2 + b2[0]);
    float h1 = tanhf(a.y + t.y * d2 + b2[1]);
    float h2 = tanhf(a.z + t.z * d2 + b2[2]);
    float h3 = tanhf(a.w + t.w * d2 + b2[3]);
    float2 t3;
    t3.x = h0 * W3[0] + h1 * W3[2] + h2 * W3[4] + h3 * W3[6];
    t3.y = h0 * W3[1] + h1 * W3[3] + h2 * W3[5] + h3 * W3[7];
    C[v] = t3;
}
__global__ void fb_node3(const float* __restrict__ dinv, const float2* __restrict__ C, const float2* __restrict__ D,
                         const float* __restrict__ b3, const float* __restrict__ Wc, const float* __restrict__ bc,
                         float* __restrict__ out, int n) {
    int v = blockIdx.x * blockDim.x + threadIdx.x;
    if (v >= n) return;
    float d = dinv[v], d2 = d * d;
    float2 t = C[v]; float2 a = D[v];
    float h0 = tanhf(a.x + t.x * d2 + b3[0]);
    float h1 = tanhf(a.y + t.y * d2 + b3[1]);
    float4 o;
    o.x = h0 * Wc[0] + h1 * Wc[4] + bc[0];
    o.y = h0 * Wc[1] + h1 * Wc[5] + bc[1];
    o.z = h0 * Wc[2] + h1 * Wc[6] + bc[2];
    o.w = h0 * Wc[3] + h1 * Wc[7] + bc[3];
    ((float4*)out)[v] = o;
    ((float2*)(out + (size_t)n * 4))[v] = make_float2(h0, h1);
}

extern "C" void kernel_launch(void* const* d_in, const int* in_sizes, int n_in,
                              void* d_out, int out_size, void* d_ws, size_t ws_size,
                              hipStream_t stream) {
    const float* x  = (const float*)d_in[0];
    const int*   ei = (const int*)  d_in[1];
    const float* W1 = (const float*)d_in[2];
    const float* b1 = (const float*)d_in[3];
    const float* W2 = (const float*)d_in[4];
    const float* b2 = (const float*)d_in[5];
    const float* W3 = (const float*)d_in[6];
    const float* b3 = (const float*)d_in[7];
    const float* Wc = (const float*)d_in[8];
    const float* bc = (const float*)d_in[9];

    const int n = in_sizes[0] / 128;
    const int E = in_sizes[1] / 2;
    const int* row = ei;       // destinations (segment ids)
    const int* col = ei + E;   // sources (gather)

    const int nb_n  = (n + 255) / 256;
    const int nb_e  = (E + 255) / 256;
    const int nb_mm = ((size_t)n * 64 + 255) / 256;
    const int nb_ov = OVF_CAP / 256;

    // fast-path workspace layout (element offsets in floats/ints)
    float* ws   = (float*)d_ws;
    float* A1   = ws;                                  // Td1 [n,4]
    float* A2   = A1 + (size_t)n * 4;                  // Td2 [n,4]
    float* Bv   = A2 + (size_t)n * 4;                  // overflow partial [n,4]
    float* C3   = Bv + (size_t)n * 4;                  // Td3 [n,2]
    float* Dv   = C3 + (size_t)n * 2;                  // overflow partial [n,2]
    float* dinv = Dv + (size_t)n * 2;                  // [n]
    int*   cnt  = (int*)(dinv + n);                    // [n]
    int*   deg  = cnt + n;                             // [n]
    int*   ovfc = deg + n;                             // [1] (+3 pad)
    int2*  ovf  = (int2*)(ovfc + 4);                   // [OVF_CAP]
    int*   slots = (int*)(ovf + OVF_CAP);              // [ELL_C * n]
    size_t need = ((size_t)(19 + ELL_C) * n + 4 + 2 * OVF_CAP) * 4;

    if (ws_size >= need) {
        init2_kernel<<<nb_n, 256, 0, stream>>>(deg, cnt, (float4*)Bv, (float2*)Dv, ovfc, n);
        build_kernel<<<nb_e, 256, 0, stream>>>(row, col, deg, cnt, slots, ovfc, ovf, n, E);
        dinv2_kernel<<<nb_n, 256, 0, stream>>>(deg, dinv, n);
        mm1_kernel<<<nb_mm, 256, 0, stream>>>(x, W1, dinv, (float4*)A1, n);

        ovf4_kernel<<<nb_ov, 256, 0, stream>>>(ovfc, ovf, (const float4*)A1, Bv);
        agg_node1<<<nb_n, 256, 0, stream>>>(cnt, slots, dinv, (const float4*)A1, (float4*)Bv, b1, W2, (float4*)A2, n);

        ovf4_kernel<<<nb_ov, 256, 0, stream>>>(ovfc, ovf, (const float4*)A2, Bv);
        agg_node2<<<nb_n, 256, 0, stream>>>(cnt, slots, dinv, (const float4*)A2, (const float4*)Bv, b2, W3, (float2*)C3, n);

        ovf2_kernel<<<nb_ov, 256, 0, stream>>>(ovfc, ovf, (const float2*)C3, Dv);
        agg_node3<<<nb_n, 256, 0, stream>>>(cnt, slots, dinv, (const float2*)C3, (const float2*)Dv, b3, Wc, bc, (float*)d_out, n);
    } else {
        // fallback: round-1 atomic path
        float4* A  = (float4*)ws;
        float4* B  = (float4*)(ws + (size_t)n * 4);
        float2* C  = (float2*)(ws + (size_t)n * 8);
        float2* D  = (float2*)(ws + (size_t)n * 10);
        float*  dv = ws + (size_t)n * 12;
        fb_init<<<nb_n, 256, 0, stream>>>(dv, B, D, n);
        fb_deg<<<nb_e, 256, 0, stream>>>(col, dv, E);
        fb_dinv<<<nb_n, 256, 0, stream>>>(dv, n);
        fb_mm1<<<nb_mm, 256, 0, stream>>>(x, W1, A, n);
        fb_edge4<<<nb_e, 256, 0, stream>>>(row, col, dv, A, (float*)B, E);
        fb_node1<<<nb_n, 256, 0, stream>>>(dv, A, B, b1, W2, n);
        fb_edge4<<<nb_e, 256, 0, stream>>>(row, col, dv, A, (float*)B, E);
        fb_node2<<<nb_n, 256, 0, stream>>>(dv, A, B, b2, W3, C, n);
        fb_edge2<<<nb_e, 256, 0, stream>>>(row, col, dv, C, (float*)D, E);
        fb_node3<<<nb_n, 256, 0, stream>>>(dv, C, D, b3, Wc, bc, (float*)d_out, n);
    }
}